// Round 9
// baseline (246.500 us; speedup 1.0000x reference)
//
#include <hip/hip_runtime.h>
#include <hip/hip_bf16.h>
#include <stdint.h>

#define HN 16      // heads
#define TT 2048    // seq len (T == S)
#define BBATCH 2
#define EE 1024
#define HD 64
#define MM 4096    // TT*BBATCH

// Q projection pre-scaled by 0.125*log2(e): exp2(q'.k) == exp(0.125*q.k).
#define SCALEQ 0.18033688011112042f

typedef __attribute__((ext_vector_type(8))) __bf16 bfrag;
typedef __attribute__((ext_vector_type(4))) float f32x4;

struct alignas(8) B4 { __bf16 a0, a1, a2, a3; };

__device__ __forceinline__ void gll16(const void* g, void* lds) {
  __builtin_amdgcn_global_load_lds(
      (const __attribute__((address_space(1))) void*)g,
      (__attribute__((address_space(3))) void*)lds, 16, 0, 0);
}

__device__ __forceinline__ f32x4 mfma_bf16(bfrag a, bfrag b, f32x4 c) {
  return __builtin_amdgcn_mfma_f32_16x16x32_bf16(a, b, c, 0, 0, 0);
}

// ---- XOR-swizzled 64-elem-row LDS tiles (16B chunk c of row r at c^(r&7)) --
__device__ __forceinline__ const bfrag* fragp(const __bf16* base, int row, int e) {
  return (const bfrag*)(base + row * 64 + ((((e >> 3) ^ row) & 7) << 3));
}
__device__ __forceinline__ void stage8(const __bf16* grow0, int gstride,
                                       __bf16* tile, int r0, int lane) {
  const int rr = lane >> 3;
  const int cl = (lane & 7) ^ rr;
  gll16(grow0 + (size_t)(r0 + rr) * gstride + cl * 8, tile + r0 * 64);
}

__device__ __forceinline__ void barrier_fence() {
  __builtin_amdgcn_s_barrier();
  __builtin_amdgcn_sched_barrier(0);
}

// ---------------- fp32 -> bf16 conversion (7 tensors in one launch) -------
struct CvtArgs {
  const float* src[7];
  __bf16* dst[7];
  int n4[7];
};

__global__ __launch_bounds__(256) void cvt_all(CvtArgs a) {
  const int z = blockIdx.z;
  const int i = blockIdx.x * 256 + threadIdx.x;
  if (i < a.n4[z]) {
    float4 v = ((const float4*)a.src[z])[i];
    B4 o = {(__bf16)v.x, (__bf16)v.y, (__bf16)v.z, (__bf16)v.w};
    ((B4*)a.dst[z])[i] = o;
  }
}

// ---------------- GEMM core (r0 form: plain syncthreads, dbuf) ------------
// Session ledger: this loop (ONE __syncthreads/iter, gll16 dbuf) measured
// 49.8 us for QKV; counted-vmcnt 57.6, 512thr 67.3, reg-staged 70.5,
// 8-phase 64.0, single-buffer 213. Do not re-schedule it.
template <int MT>
__device__ __forceinline__ void gemm2(const __bf16* __restrict__ X,
                                      const __bf16* __restrict__ W,
                                      const float* __restrict__ bias,
                                      void* __restrict__ out, int mode,
                                      float scale, int m0, int n0,
                                      __bf16* As0, __bf16* As1,
                                      __bf16* Bs0, __bf16* Bs1) {
  const int tid = threadIdx.x, lane = tid & 63, w = tid >> 6;
  const int wm = w >> 1, wn = w & 1;
  const int quad = lane >> 4, l16 = lane & 15;
  constexpr int FM = MT / 32;   // m-frags per wave

  auto stageAB = [&](int buf, int k0) {
    __bf16* A = buf ? As1 : As0;
    __bf16* B = buf ? Bs1 : Bs0;
    #pragma unroll
    for (int c = 0; c < FM; ++c)
      stage8(X + (size_t)m0 * EE + k0, EE, A, w * (MT / 4) + c * 8, lane);
    #pragma unroll
    for (int c = 0; c < 4; ++c)
      stage8(W + (size_t)n0 * EE + k0, EE, B, w * 32 + c * 8, lane);
  };

  stageAB(0, 0);

  f32x4 acc[FM][4] = {};

  for (int it = 0; it < EE / 64; ++it) {
    const int cur = it & 1;
    __syncthreads();                 // buf[cur] staged; prior reads done
    if (it + 1 < EE / 64) stageAB(1 - cur, (it + 1) * 64);

    const __bf16* A = cur ? As1 : As0;
    const __bf16* B = cur ? Bs1 : Bs0;
    #pragma unroll
    for (int ks = 0; ks < 2; ++ks) {
      bfrag a[FM], b[4];
      #pragma unroll
      for (int f = 0; f < FM; ++f)
        a[f] = *fragp(A, wm * (MT / 2) + f * 16 + l16, ks * 32 + quad * 8);
      #pragma unroll
      for (int f = 0; f < 4; ++f)
        b[f] = *fragp(B, wn * 64 + f * 16 + l16, ks * 32 + quad * 8);
      #pragma unroll
      for (int fm = 0; fm < FM; ++fm)
        #pragma unroll
        for (int fn = 0; fn < 4; ++fn)
          acc[fm][fn] = mfma_bf16(a[fm], b[fn], acc[fm][fn]);
    }
  }

  float bv[4];
  #pragma unroll
  for (int fn = 0; fn < 4; ++fn) bv[fn] = bias[n0 + wn * 64 + fn * 16 + l16];

  #pragma unroll
  for (int fm = 0; fm < FM; ++fm) {
    #pragma unroll
    for (int r = 0; r < 4; ++r) {
      const int gm = m0 + wm * (MT / 2) + fm * 16 + quad * 4 + r;
      #pragma unroll
      for (int fn = 0; fn < 4; ++fn) {
        const int gn = n0 + wn * 64 + fn * 16 + l16;
        const float v = (acc[fm][fn][r] + bv[fn]) * scale;
        if (mode == 0) {
          const int t = gm >> 1, bb = gm & 1, h = gn >> 6, d = gn & 63;
          ((__bf16*)out)[(((size_t)(bb * HN + h)) * TT + t) * HD + d] = (__bf16)v;
        } else if (mode == 2) {
          const int s = gm >> 1, bb = gm & 1, h = gn >> 6, d = gn & 63;
          ((__bf16*)out)[(((size_t)(bb * HN + h)) * HD + d) * TT + s] = (__bf16)v;
        } else {
          ((float*)out)[(size_t)gm * EE + gn] = v;
        }
      }
    }
  }
}

// flat grid 768: bx = m + 32*(n + 8*z). bx%8 == m%8 -> the 8 n-blocks
// sharing one A-tile land on one XCD (A-tiles 1MB + B 2MB fit 4MB L2).
__global__ __launch_bounds__(256, 2) void gemm_qkv(
    const __bf16* __restrict__ xq, const __bf16* __restrict__ xk,
    const __bf16* __restrict__ xv, const __bf16* __restrict__ wq,
    const __bf16* __restrict__ wk, const __bf16* __restrict__ wv,
    const float* __restrict__ bq, const float* __restrict__ bk,
    const float* __restrict__ bv, __bf16* __restrict__ qo,
    __bf16* __restrict__ ko, __bf16* __restrict__ vo) {
  __shared__ __bf16 As[2][128 * 64];   // 32KB
  __shared__ __bf16 Bs[2][128 * 64];   // 32KB
  const int bx = blockIdx.x;
  const int m = bx & 31, n = (bx >> 5) & 7, z = bx >> 8;
  const __bf16 *X, *W;
  const float* bias;
  __bf16* out;
  int mode;
  float scale;
  if (z == 0)      { X = xq; W = wq; bias = bq; out = qo; mode = 0; scale = SCALEQ; }
  else if (z == 1) { X = xk; W = wk; bias = bk; out = ko; mode = 0; scale = 1.0f; }
  else             { X = xv; W = wv; bias = bv; out = vo; mode = 2; scale = 1.0f; }
  gemm2<128>(X, W, bias, out, mode, scale, m * 128, n * 128,
             As[0], As[1], Bs[0], Bs[1]);
}

// ---------------- flash attention fwd: O (normalized) + linv -------------
// r9: 64-row t-blocks, shared K/V tile across all 4 waves (no p-split).
// Mechanism: r8 showed MfmaUtil~31 + VALUBusy~31 with 2 blocks/CU -- the
// MFMA and VALU phases of a wave serialize and there aren't enough
// independent barrier groups to fill the stalls. This version: LDS 32KB
// (4 blocks/CU), grid 1024 (exactly 4/CU), each wave owns 16 t-rows and
// computes its COMPLETE l and O (s-loop covers all 2048) -> the whole
// Lsum/om LDS merge epilogue disappears. K/V for the 4 bh of an XCD =
// 2MB, fits its 4MB L2. Counted-vmcnt staging (r8 pattern, counts
// halved): per iter issue V-regs(next,2)+K-gll16(next,2); vmcnt(2)
// retires K(cur)+V(next), keeps K(next) flying; ds_write V; lgkmcnt(0).
__global__ __launch_bounds__(256, 4) void attn_fwd(const __bf16* __restrict__ qb,
                                                   const __bf16* __restrict__ kb,
                                                   const __bf16* __restrict__ vtb,
                                                   __bf16* __restrict__ ob,
                                                   float* __restrict__ linv_ws) {
  __shared__ __bf16 kv[2][2][64 * 64];   // [K=0/V=1][buf] 32KB

  const int tid = threadIdx.x, lane = tid & 63, w = tid >> 6;
  const int quad = lane >> 4, l16 = lane & 15;

  const int bx = blockIdx.x;
  const int xcd = bx & 7, slot = bx >> 3;        // slot 0..127
  const int bhi = xcd * 4 + (slot >> 5);         // 4 bh per XCD
  const int t0 = (slot & 31) * 64;
  const int b = bhi >> 4, h = bhi & 15;
  const size_t bh = (size_t)(b * HN + h);

  const __bf16* qbase = qb + (bh * TT + t0) * HD;
  const __bf16* kbase = kb + bh * TT * HD;
  const __bf16* vbase = vtb + bh * HD * TT;

  // ---- V reg-staging (r8 permuted layout: group g of a 64-row at 16B
  //      chunk c'=(g>=8)*4+(g&3), half (g>>2)&1, chunk XOR row&7 -> PV
  //      A-operand is one conflict-free ds_read_b128 via fragp)
  const int rr = lane >> 3, cs = lane & 7;
  uint4 vv[2];
  auto loadV = [&](int s1) {
    #pragma unroll
    for (int c = 0; c < 2; ++c)
      vv[c] = *(const uint4*)(vbase + s1 + (size_t)(w * 16 + c * 8 + rr) * TT + cs * 8);
  };
  const int c0 = ((cs >= 4) ? 4 : 0) + ((2 * cs) & 3);
  const int c1 = ((cs >= 4) ? 4 : 0) + ((2 * cs + 1) & 3);
  const int h4 = ((cs >> 1) & 1) * 4;   // half offset in elements
  auto writeV = [&](__bf16* Vb) {
    #pragma unroll
    for (int c = 0; c < 2; ++c) {
      const int r = w * 16 + c * 8 + rr;     // r&7 == rr
      __bf16* rowp = Vb + r * 64;
      uint2 a; a.x = vv[c].x; a.y = vv[c].y;
      uint2 d; d.x = vv[c].z; d.y = vv[c].w;
      *(uint2*)(rowp + ((c0 ^ rr) << 3) + h4) = a;   // group 2cs
      *(uint2*)(rowp + ((c1 ^ rr) << 3) + h4) = d;   // group 2cs+1
    }
  };
  auto stageK = [&](int s1, __bf16* Kb) {
    #pragma unroll
    for (int c = 0; c < 2; ++c)
      stage8(kbase + (size_t)s1 * HD, HD, Kb, w * 16 + c * 8, lane);
  };

  // ---- Q fragment: wave w owns t-rows t0 + w*16 + l16
  bfrag qf[2];
  #pragma unroll
  for (int ks = 0; ks < 2; ++ks)
    qf[ks] = *(const bfrag*)(qbase +
        (size_t)(w * 16 + l16) * HD + ks * 32 + quad * 8);
  __builtin_amdgcn_sched_barrier(0);

  // ---- prologue: V(0) regs + K(0) gll16; retire Q+V(0), keep K(0) flying
  loadV(0);
  stageK(0, kv[0][0]);
  asm volatile("s_waitcnt vmcnt(2)" ::: "memory");
  __builtin_amdgcn_sched_barrier(0);
  writeV(kv[1][0]);

  bfrag ones;
  {
    union { short s[8]; bfrag v; } u;
    #pragma unroll
    for (int i = 0; i < 8; ++i) u.s[i] = 0x3F80;   // bf16 1.0
    ones = u.v;
  }

  f32x4 oacc[4] = {};   // O^T rows d=fm*16+quad*4+r, col t=l16
  f32x4 lacc = {};      // row sums via ones-MFMA (identical across r)

  for (int it = 0; it < 32; ++it) {
    const int cur = it & 1;
    barrier_fence();                     // readers of buf[1-cur] done
    if (it + 1 < 32) {
      const int s1 = (it + 1) * 64;
      loadV(s1);                         // 2 vmem -> regs
      stageK(s1, kv[0][1 - cur]);        // 2 vmem -> LDS
      // outstanding: K(cur)2 + V(next)2 + K(next)2 -> retire first 4
      asm volatile("s_waitcnt vmcnt(2)" ::: "memory");
      __builtin_amdgcn_sched_barrier(0);
      writeV(kv[1][1 - cur]);
      asm volatile("s_waitcnt lgkmcnt(0)" ::: "memory");
      __builtin_amdgcn_sched_barrier(0);
    } else {
      asm volatile("s_waitcnt vmcnt(0)" ::: "memory");
    }
    barrier_fence();                     // cur K landed; next V visible

    // ---- S^T[s][t] = K.Q
    f32x4 sacc[4] = {};
    #pragma unroll
    for (int ks = 0; ks < 2; ++ks) {
      bfrag kf[4];
      #pragma unroll
      for (int fm = 0; fm < 4; ++fm)
        kf[fm] = *fragp(kv[0][cur], fm * 16 + l16, ks * 32 + quad * 8);
      __builtin_amdgcn_s_setprio(1);
      #pragma unroll
      for (int fm = 0; fm < 4; ++fm)
        sacc[fm] = mfma_bf16(kf[fm], qf[ks], sacc[fm]);
      __builtin_amdgcn_s_setprio(0);
    }

    // ---- exp2 in registers; pack into x32 B-operands
    union PB { __bf16 hh[8]; bfrag v; } pb[2];
    #pragma unroll
    for (int fm = 0; fm < 4; ++fm) {
      const float p0 = __builtin_amdgcn_exp2f(sacc[fm][0]);
      const float p1 = __builtin_amdgcn_exp2f(sacc[fm][1]);
      const float p2 = __builtin_amdgcn_exp2f(sacc[fm][2]);
      const float p3 = __builtin_amdgcn_exp2f(sacc[fm][3]);
      const int hb = (fm & 1) * 4;
      pb[fm >> 1].hh[hb + 0] = (__bf16)p0;
      pb[fm >> 1].hh[hb + 1] = (__bf16)p1;
      pb[fm >> 1].hh[hb + 2] = (__bf16)p2;
      pb[fm >> 1].hh[hb + 3] = (__bf16)p3;
    }

    // ---- O^T += V^T.P^T ; l += 1.P^T on the MFMA pipe
    #pragma unroll
    for (int ks = 0; ks < 2; ++ks) {
      bfrag vf[4];
      #pragma unroll
      for (int fm = 0; fm < 4; ++fm)   // single b128, conflict-free
        vf[fm] = *fragp(kv[1][cur], fm * 16 + l16, ks * 32 + quad * 8);
      __builtin_amdgcn_s_setprio(1);
      lacc = mfma_bf16(ones, pb[ks].v, lacc);
      #pragma unroll
      for (int fm = 0; fm < 4; ++fm)
        oacc[fm] = mfma_bf16(vf[fm], pb[ks].v, oacc[fm]);
      __builtin_amdgcn_s_setprio(0);
    }
  }

  // ---- epilogue: fully in-register (each wave owns complete rows)
  const int t = t0 + w * 16 + l16;
  const float linv = 1.0f / lacc[0];
  if (quad == 0) linv_ws[bh * TT + t] = linv;
  #pragma unroll
  for (int fm = 0; fm < 4; ++fm) {
    B4 o;
    __bf16* op = &o.a0;
    #pragma unroll
    for (int r = 0; r < 4; ++r) op[r] = (__bf16)(oacc[fm][r] * linv);
    *(B4*)(ob + ((size_t)t * BBATCH + b) * EE + h * HD + fm * 16 + quad * 4) = o;
  }
}

// ---------------- avg_w body (r2 form) -----------------------------------
__device__ void avg_body(const __bf16* __restrict__ qb,
                         const __bf16* __restrict__ kb,
                         const float* __restrict__ linv_ws,
                         float* __restrict__ avg_out, int bx,
                         __bf16* Qs0, __bf16* Qs1,
                         __bf16* Ks0, __bf16* Ks1) {
  const int tid = threadIdx.x, lane = tid & 63, w = tid >> 6;
  const int wm = w >> 1, wn = w & 1;
  const int quad = lane >> 4, l16 = lane & 15;

  const int xcd = bx & 7, slot = bx >> 3;
  const int bti = xcd * 4 + (slot >> 4);
  const int s0 = (slot & 15) * 128;
  const int b = bti >> 4, t0 = (bti & 15) * 128;

  const __bf16* qt = qb + (((size_t)b * HN) * TT + t0) * HD;
  const __bf16* kt = kb + (((size_t)b * HN) * TT + s0) * HD;
  const float* lrow0 = linv_ws + ((size_t)b * HN) * TT + t0 + wm * 64;

  #pragma unroll
  for (int c = 0; c < 4; ++c) {
    stage8(qt, HD, Qs0, w * 32 + c * 8, lane);
    stage8(kt, HD, Ks0, w * 32 + c * 8, lane);
  }

  f32x4 aacc[4][4] = {};

  for (int h = 0; h < HN; ++h) {
    const int cur = h & 1;
    barrier_fence();
    if (h + 1 < HN) {
      const __bf16* qn = qt + (size_t)(h + 1) * TT * HD;
      const __bf16* kn = kt + (size_t)(h + 1) * TT * HD;
      __bf16* Qn = cur ? Qs0 : Qs1;
      __bf16* Kn = cur ? Ks0 : Ks1;
      #pragma unroll
      for (int c = 0; c < 4; ++c) {
        stage8(qn, HD, Qn, w * 32 + c * 8, lane);
        stage8(kn, HD, Kn, w * 32 + c * 8, lane);
      }
      asm volatile("s_waitcnt vmcnt(8)" ::: "memory");
    } else {
      asm volatile("s_waitcnt vmcnt(0)" ::: "memory");
    }
    barrier_fence();

    const __bf16* Qc = cur ? Qs1 : Qs0;
    const __bf16* Kc = cur ? Ks1 : Ks0;
    f32x4 sacc[4][4] = {};
    #pragma unroll
    for (int ks = 0; ks < 2; ++ks) {
      bfrag qf4[4], kf4[4];
      #pragma unroll
      for (int f = 0; f < 4; ++f)
        qf4[f] = *fragp(Qc, wm * 64 + f * 16 + l16, ks * 32 + quad * 8);
      #pragma unroll
      for (int f = 0; f < 4; ++f)
        kf4[f] = *fragp(Kc, wn * 64 + f * 16 + l16, ks * 32 + quad * 8);
      #pragma unroll
      for (int fm = 0; fm < 4; ++fm)
        #pragma unroll
        for (int fn = 0; fn < 4; ++fn)
          sacc[fm][fn] = mfma_bf16(qf4[fm], kf4[fn], sacc[fm][fn]);
    }

    const float* lr = lrow0 + (size_t)h * TT;
    f32x4 lvv[4];
    #pragma unroll
    for (int fm = 0; fm < 4; ++fm)
      lvv[fm] = *(const f32x4*)(lr + fm * 16 + quad * 4);

    #pragma unroll
    for (int fm = 0; fm < 4; ++fm)
      #pragma unroll
      for (int fn = 0; fn < 4; ++fn)
        #pragma unroll
        for (int r = 0; r < 4; ++r)
          aacc[fm][fn][r] += __builtin_amdgcn_exp2f(sacc[fm][fn][r]) * lvv[fm][r];
  }

  const float invh = 1.0f / (float)HN;
  #pragma unroll
  for (int fm = 0; fm < 4; ++fm)
    #pragma unroll
    for (int r = 0; r < 4; ++r) {
      const int t = t0 + wm * 64 + fm * 16 + quad * 4 + r;
      #pragma unroll
      for (int fn = 0; fn < 4; ++fn) {
        const int s = s0 + wn * 64 + fn * 16 + l16;
        avg_out[((size_t)b * TT + t) * TT + s] = aacc[fm][fn][r] * invh;
      }
    }
}

// ---------------- tail: avg_attn (blocks 0..511) + gemm_o (512..1023) ----
struct TailAvg { __bf16 Qs[2][128 * 64]; __bf16 Ks[2][128 * 64]; };  // 64KB
struct TailGo  { __bf16 As[2][64 * 64];  __bf16 Bs[2][128 * 64]; }; // 48KB
union TailSh { TailAvg a; TailGo g; };

__global__ __launch_bounds__(256, 2) void tail_fused(
    const __bf16* __restrict__ qb, const __bf16* __restrict__ kb,
    const float* __restrict__ linv_ws, float* __restrict__ avg_out,
    const __bf16* __restrict__ ob, const __bf16* __restrict__ wo,
    const float* __restrict__ bo, float* __restrict__ out) {
  __shared__ TailSh sh;
  const int bx = blockIdx.x;
  if (bx < 512) {
    avg_body(qb, kb, linv_ws, avg_out, bx,
             sh.a.Qs[0], sh.a.Qs[1], sh.a.Ks[0], sh.a.Ks[1]);
  } else {
    const int b2 = bx - 512;
    const int m = b2 & 63, n = b2 >> 6;
    gemm2<64>(ob, wo, bo, out, 3, 1.0f, m * 64, n * 128,
              sh.g.As[0], sh.g.As[1], sh.g.Bs[0], sh.g.Bs[1]);
  }
}

extern "C" void kernel_launch(void* const* d_in, const int* in_sizes, int n_in,
                              void* d_out, int out_size, void* d_ws, size_t ws_size,
                              hipStream_t stream) {
  (void)in_sizes; (void)n_in; (void)out_size; (void)ws_size;
  const float* query = (const float*)d_in[0];
  const float* key   = (const float*)d_in[1];
  const float* value = (const float*)d_in[2];
  const float* Wq = (const float*)d_in[3];
  const float* bq = (const float*)d_in[4];
  const float* Wk = (const float*)d_in[5];
  const float* bk = (const float*)d_in[6];
  const float* Wv = (const float*)d_in[7];
  const float* bv = (const float*)d_in[8];
  const float* Wo = (const float*)d_in[9];
  const float* bo = (const float*)d_in[10];

  char* ws = (char*)d_ws;
  size_t off = 0;
  auto wsalloc = [&](size_t bytes) -> void* {
    void* p = ws + off;
    off += (bytes + 255) & ~(size_t)255;
    return p;
  };
  const size_t XE = (size_t)MM * EE;
  const size_t WE = (size_t)EE * EE;
  __bf16* xq   = (__bf16*)wsalloc(XE * 2);
  __bf16* xk   = (__bf16*)wsalloc(XE * 2);
  __bf16* xv   = (__bf16*)wsalloc(XE * 2);
  __bf16* wqb  = (__bf16*)wsalloc(WE * 2);
  __bf16* wkb  = (__bf16*)wsalloc(WE * 2);
  __bf16* wvb  = (__bf16*)wsalloc(WE * 2);
  __bf16* wob  = (__bf16*)wsalloc(WE * 2);
  __bf16* qbuf = (__bf16*)wsalloc(XE * 2);
  __bf16* kbuf = (__bf16*)wsalloc(XE * 2);
  __bf16* vtbuf= (__bf16*)wsalloc(XE * 2);
  __bf16* obuf = (__bf16*)wsalloc(XE * 2);
  float* linv  = (float*)wsalloc((size_t)BBATCH * HN * TT * 4);

  CvtArgs ca;
  ca.src[0] = query; ca.dst[0] = xq;  ca.n4[0] = (int)(XE / 4);
  ca.src[1] = key;   ca.dst[1] = xk;  ca.n4[1] = (int)(XE / 4);
  ca.src[2] = value; ca.dst[2] = xv;  ca.n4[2] = (int)(XE / 4);
  ca.src[3] = Wq;    ca.dst[3] = wqb; ca.n4[3] = (int)(WE / 4);
  ca.src[4] = Wk;    ca.dst[4] = wkb; ca.n4[4] = (int)(WE / 4);
  ca.src[5] = Wv;    ca.dst[5] = wvb; ca.n4[5] = (int)(WE / 4);
  ca.src[6] = Wo;    ca.dst[6] = wob; ca.n4[6] = (int)(WE / 4);
  cvt_all<<<dim3(4096, 1, 7), 256, 0, stream>>>(ca);

  gemm_qkv<<<dim3(768), 256, 0, stream>>>(xq, xk, xv, wqb, wkb, wvb,
                                          bq, bk, bv, qbuf, kbuf, vtbuf);

  attn_fwd<<<dim3(1024), 256, 0, stream>>>(qbuf, kbuf, vtbuf, obuf, linv);

  float* avg_out = (float*)d_out + (size_t)TT * BBATCH * EE;
  tail_fused<<<dim3(1024), 256, 0, stream>>>(qbuf, kbuf, linv, avg_out,
                                             obuf, wob, bo, (float*)d_out);
}

// Round 10
// 240.745 us; speedup vs baseline: 1.0239x; 1.0239x over previous
//
#include <hip/hip_runtime.h>
#include <hip/hip_bf16.h>
#include <stdint.h>

#define HN 16      // heads
#define TT 2048    // seq len (T == S)
#define BBATCH 2
#define EE 1024
#define HD 64
#define MM 4096    // TT*BBATCH

// Q projection pre-scaled by 0.125*log2(e): exp2(q'.k) == exp(0.125*q.k).
#define SCALEQ 0.18033688011112042f

typedef __attribute__((ext_vector_type(8))) __bf16 bfrag;
typedef __attribute__((ext_vector_type(4))) float f32x4;

struct alignas(8) B4 { __bf16 a0, a1, a2, a3; };

__device__ __forceinline__ void gll16(const void* g, void* lds) {
  __builtin_amdgcn_global_load_lds(
      (const __attribute__((address_space(1))) void*)g,
      (__attribute__((address_space(3))) void*)lds, 16, 0, 0);
}

__device__ __forceinline__ f32x4 mfma_bf16(bfrag a, bfrag b, f32x4 c) {
  return __builtin_amdgcn_mfma_f32_16x16x32_bf16(a, b, c, 0, 0, 0);
}

// ---- XOR-swizzled 64-elem-row LDS tiles (16B chunk c of row r at c^(r&7)) --
__device__ __forceinline__ const bfrag* fragp(const __bf16* base, int row, int e) {
  return (const bfrag*)(base + row * 64 + ((((e >> 3) ^ row) & 7) << 3));
}
__device__ __forceinline__ void stage8(const __bf16* grow0, int gstride,
                                       __bf16* tile, int r0, int lane) {
  const int rr = lane >> 3;
  const int cl = (lane & 7) ^ rr;
  gll16(grow0 + (size_t)(r0 + rr) * gstride + cl * 8, tile + r0 * 64);
}

__device__ __forceinline__ void barrier_fence() {
  __builtin_amdgcn_s_barrier();
  __builtin_amdgcn_sched_barrier(0);
}

// ---------------- fp32 -> bf16 conversion (7 tensors in one launch) -------
struct CvtArgs {
  const float* src[7];
  __bf16* dst[7];
  int n4[7];
};

__global__ __launch_bounds__(256) void cvt_all(CvtArgs a) {
  const int z = blockIdx.z;
  const int i = blockIdx.x * 256 + threadIdx.x;
  if (i < a.n4[z]) {
    float4 v = ((const float4*)a.src[z])[i];
    B4 o = {(__bf16)v.x, (__bf16)v.y, (__bf16)v.z, (__bf16)v.w};
    ((B4*)a.dst[z])[i] = o;
  }
}

// ---------------- GEMM core (r0 form: plain syncthreads, dbuf) ------------
// Session ledger: this loop (ONE __syncthreads/iter, gll16 dbuf) measured
// 49.8 us for QKV; counted-vmcnt 57.6, 512thr 67.3, reg-staged 70.5,
// 8-phase 64.0, single-buffer 213. Work-per-barrier-interval is the
// controlling variable (r1/r6/r9 all confirm). Do not re-schedule it.
template <int MT>
__device__ __forceinline__ void gemm2(const __bf16* __restrict__ X,
                                      const __bf16* __restrict__ W,
                                      const float* __restrict__ bias,
                                      void* __restrict__ out, int mode,
                                      float scale, int m0, int n0,
                                      __bf16* As0, __bf16* As1,
                                      __bf16* Bs0, __bf16* Bs1) {
  const int tid = threadIdx.x, lane = tid & 63, w = tid >> 6;
  const int wm = w >> 1, wn = w & 1;
  const int quad = lane >> 4, l16 = lane & 15;
  constexpr int FM = MT / 32;   // m-frags per wave

  auto stageAB = [&](int buf, int k0) {
    __bf16* A = buf ? As1 : As0;
    __bf16* B = buf ? Bs1 : Bs0;
    #pragma unroll
    for (int c = 0; c < FM; ++c)
      stage8(X + (size_t)m0 * EE + k0, EE, A, w * (MT / 4) + c * 8, lane);
    #pragma unroll
    for (int c = 0; c < 4; ++c)
      stage8(W + (size_t)n0 * EE + k0, EE, B, w * 32 + c * 8, lane);
  };

  stageAB(0, 0);

  f32x4 acc[FM][4] = {};

  for (int it = 0; it < EE / 64; ++it) {
    const int cur = it & 1;
    __syncthreads();                 // buf[cur] staged; prior reads done
    if (it + 1 < EE / 64) stageAB(1 - cur, (it + 1) * 64);

    const __bf16* A = cur ? As1 : As0;
    const __bf16* B = cur ? Bs1 : Bs0;
    #pragma unroll
    for (int ks = 0; ks < 2; ++ks) {
      bfrag a[FM], b[4];
      #pragma unroll
      for (int f = 0; f < FM; ++f)
        a[f] = *fragp(A, wm * (MT / 2) + f * 16 + l16, ks * 32 + quad * 8);
      #pragma unroll
      for (int f = 0; f < 4; ++f)
        b[f] = *fragp(B, wn * 64 + f * 16 + l16, ks * 32 + quad * 8);
      #pragma unroll
      for (int fm = 0; fm < FM; ++fm)
        #pragma unroll
        for (int fn = 0; fn < 4; ++fn)
          acc[fm][fn] = mfma_bf16(a[fm], b[fn], acc[fm][fn]);
    }
  }

  float bv[4];
  #pragma unroll
  for (int fn = 0; fn < 4; ++fn) bv[fn] = bias[n0 + wn * 64 + fn * 16 + l16];

  #pragma unroll
  for (int fm = 0; fm < FM; ++fm) {
    #pragma unroll
    for (int r = 0; r < 4; ++r) {
      const int gm = m0 + wm * (MT / 2) + fm * 16 + quad * 4 + r;
      #pragma unroll
      for (int fn = 0; fn < 4; ++fn) {
        const int gn = n0 + wn * 64 + fn * 16 + l16;
        const float v = (acc[fm][fn][r] + bv[fn]) * scale;
        if (mode == 0) {
          const int t = gm >> 1, bb = gm & 1, h = gn >> 6, d = gn & 63;
          ((__bf16*)out)[(((size_t)(bb * HN + h)) * TT + t) * HD + d] = (__bf16)v;
        } else if (mode == 2) {
          const int s = gm >> 1, bb = gm & 1, h = gn >> 6, d = gn & 63;
          ((__bf16*)out)[(((size_t)(bb * HN + h)) * HD + d) * TT + s] = (__bf16)v;
        } else {
          ((float*)out)[(size_t)gm * EE + gn] = v;
        }
      }
    }
  }
}

// flat grid 768: bx = m + 32*(n + 8*z). bx%8 == m%8 -> the 8 n-blocks
// sharing one A-tile land on one XCD (A-tiles 1MB + B 2MB fit 4MB L2).
__global__ __launch_bounds__(256, 2) void gemm_qkv(
    const __bf16* __restrict__ xq, const __bf16* __restrict__ xk,
    const __bf16* __restrict__ xv, const __bf16* __restrict__ wq,
    const __bf16* __restrict__ wk, const __bf16* __restrict__ wv,
    const float* __restrict__ bq, const float* __restrict__ bk,
    const float* __restrict__ bv, __bf16* __restrict__ qo,
    __bf16* __restrict__ ko, __bf16* __restrict__ vo) {
  __shared__ __bf16 As[2][128 * 64];   // 32KB
  __shared__ __bf16 Bs[2][128 * 64];   // 32KB
  const int bx = blockIdx.x;
  const int m = bx & 31, n = (bx >> 5) & 7, z = bx >> 8;
  const __bf16 *X, *W;
  const float* bias;
  __bf16* out;
  int mode;
  float scale;
  if (z == 0)      { X = xq; W = wq; bias = bq; out = qo; mode = 0; scale = SCALEQ; }
  else if (z == 1) { X = xk; W = wk; bias = bk; out = ko; mode = 0; scale = 1.0f; }
  else             { X = xv; W = wv; bias = bv; out = vo; mode = 2; scale = 1.0f; }
  gemm2<128>(X, W, bias, out, mode, scale, m * 128, n * 128,
             As[0], As[1], Bs[0], Bs[1]);
}

// ---------------- flash attention fwd: O (normalized) + linv -------------
// r8 form (session-best, 46.8us): 128-row t-blocks, p-split s-halves,
// 2 blocks/CU, 36 MFMA/barrier-interval. V reg-staged into GROUP-PERMUTED
// swizzled layout -> PV A-operand is ONE conflict-free ds_read_b128
// (bank conflicts 2.36M -> 262K; time-neutral -> attn is phase-serialization
// bound, not LDS-bound). r9's 64-row/4-block variant: 52.8us (refuted).
__global__ __launch_bounds__(256, 2) void attn_fwd(const __bf16* __restrict__ qb,
                                                   const __bf16* __restrict__ kb,
                                                   const __bf16* __restrict__ vtb,
                                                   __bf16* __restrict__ ob,
                                                   float* __restrict__ linv_ws) {
  union Sh {
    __bf16 kv[2][2][2][64 * 64];  // [pair][K=0/V=1][buf] 64KB
    float om[2][64 * 64];         // epilogue O-merge scratch (32KB, aliased)
  };
  __shared__ Sh sm;
  __shared__ float Lsum[2][128];
  __shared__ float LinvS[128];

  const int tid = threadIdx.x, lane = tid & 63, w = tid >> 6;
  const int p = w >> 1, tw = w & 1;
  const int quad = lane >> 4, l16 = lane & 15;

  const int bx = blockIdx.x;
  const int xcd = bx & 7, slot = bx >> 3;
  const int bhi = xcd * 4 + (slot >> 4);
  const int t0 = (slot & 15) * 128;
  const int b = bhi >> 4, h = bhi & 15;
  const size_t bh = (size_t)(b * HN + h);

  const __bf16* qbase = qb + (bh * TT + t0) * HD;
  const __bf16* kbase = kb + bh * TT * HD;
  const __bf16* vbase = vtb + bh * HD * TT;
  const int sBase = p * 1024;

  // ---- V reg-staging helpers (permuted layout; see header comment)
  const int rr = lane >> 3, cs = lane & 7;
  uint4 vv[4];
  auto loadV = [&](int s1) {
    #pragma unroll
    for (int c = 0; c < 4; ++c)
      vv[c] = *(const uint4*)(vbase + s1 + (size_t)(tw * 32 + c * 8 + rr) * TT + cs * 8);
  };
  const int c0 = ((cs >= 4) ? 4 : 0) + ((2 * cs) & 3);
  const int c1 = ((cs >= 4) ? 4 : 0) + ((2 * cs + 1) & 3);
  const int h4 = ((cs >> 1) & 1) * 4;   // half offset in elements (0 or 4)
  auto writeV = [&](__bf16* Vb) {
    #pragma unroll
    for (int c = 0; c < 4; ++c) {
      const int r = tw * 32 + c * 8 + rr;     // r&7 == rr
      __bf16* rowp = Vb + r * 64;
      uint2 a; a.x = vv[c].x; a.y = vv[c].y;
      uint2 d; d.x = vv[c].z; d.y = vv[c].w;
      *(uint2*)(rowp + ((c0 ^ rr) << 3) + h4) = a;   // group 2cs
      *(uint2*)(rowp + ((c1 ^ rr) << 3) + h4) = d;   // group 2cs+1
    }
  };

  // ---- Q fragments first (oldest vmem -> retired by first counted wait)
  bfrag qf[4][2];
  #pragma unroll
  for (int fn = 0; fn < 4; ++fn)
    #pragma unroll
    for (int ks = 0; ks < 2; ++ks)
      qf[fn][ks] = *(const bfrag*)(qbase +
          (size_t)(tw * 64 + fn * 16 + l16) * HD + ks * 32 + quad * 8);
  __builtin_amdgcn_sched_barrier(0);

  // ---- prologue: V(0) regs + K(0) gll16; retire qf+V(0), keep K(0) flying
  loadV(sBase);
  #pragma unroll
  for (int c = 0; c < 4; ++c)
    stage8(kbase + (size_t)sBase * HD, HD, sm.kv[p][0][0], tw * 32 + c * 8, lane);
  asm volatile("s_waitcnt vmcnt(4)" ::: "memory");
  __builtin_amdgcn_sched_barrier(0);
  writeV(sm.kv[p][1][0]);

  bfrag ones;
  {
    union { short s[8]; bfrag v; } u;
    #pragma unroll
    for (int i = 0; i < 8; ++i) u.s[i] = 0x3F80;   // bf16 1.0
    ones = u.v;
  }

  f32x4 oacc[4][4] = {};   // [fm_d][fn_t] of O^T
  f32x4 lacc[4] = {};      // row sums via ones-MFMA

  for (int it = 0; it < 16; ++it) {
    const int cur = it & 1;
    barrier_fence();                     // readers of buf[1-cur] done
    if (it + 1 < 16) {
      const int s1 = sBase + (it + 1) * 64;
      loadV(s1);                         // 4 vmem -> regs
      #pragma unroll
      for (int c = 0; c < 4; ++c)        // 4 vmem -> LDS
        stage8(kbase + (size_t)s1 * HD, HD, sm.kv[p][0][1 - cur], tw * 32 + c * 8, lane);
      // outstanding: K(cur)4 + V(next)4 + K(next)4 -> retire first 8
      asm volatile("s_waitcnt vmcnt(4)" ::: "memory");
      __builtin_amdgcn_sched_barrier(0);
      writeV(sm.kv[p][1][1 - cur]);
      asm volatile("s_waitcnt lgkmcnt(0)" ::: "memory");
      __builtin_amdgcn_sched_barrier(0);
    } else {
      asm volatile("s_waitcnt vmcnt(0)" ::: "memory");
    }
    barrier_fence();                     // cur K landed; next V visible

    // ---- S^T[s][t] = K.Q
    f32x4 sacc[4][4] = {};
    #pragma unroll
    for (int ks = 0; ks < 2; ++ks) {
      bfrag kf[4];
      #pragma unroll
      for (int fm = 0; fm < 4; ++fm)
        kf[fm] = *fragp(sm.kv[p][0][cur], fm * 16 + l16, ks * 32 + quad * 8);
      __builtin_amdgcn_s_setprio(1);
      #pragma unroll
      for (int fm = 0; fm < 4; ++fm)
        #pragma unroll
        for (int fn = 0; fn < 4; ++fn)
          sacc[fm][fn] = mfma_bf16(kf[fm], qf[fn][ks], sacc[fm][fn]);
      __builtin_amdgcn_s_setprio(0);
    }

    // ---- exp2 in registers; pack into x32 B-operands
    union PB { __bf16 hh[8]; bfrag v; } pb[2][4];
    #pragma unroll
    for (int fm = 0; fm < 4; ++fm)
      #pragma unroll
      for (int fn = 0; fn < 4; ++fn) {
        const float p0 = __builtin_amdgcn_exp2f(sacc[fm][fn][0]);
        const float p1 = __builtin_amdgcn_exp2f(sacc[fm][fn][1]);
        const float p2 = __builtin_amdgcn_exp2f(sacc[fm][fn][2]);
        const float p3 = __builtin_amdgcn_exp2f(sacc[fm][fn][3]);
        const int hb = (fm & 1) * 4;
        pb[fm >> 1][fn].hh[hb + 0] = (__bf16)p0;
        pb[fm >> 1][fn].hh[hb + 1] = (__bf16)p1;
        pb[fm >> 1][fn].hh[hb + 2] = (__bf16)p2;
        pb[fm >> 1][fn].hh[hb + 3] = (__bf16)p3;
      }

    // ---- O^T += V^T.P^T ; l += 1.P^T on the MFMA pipe
    #pragma unroll
    for (int ks = 0; ks < 2; ++ks) {
      bfrag vf[4];
      #pragma unroll
      for (int fm = 0; fm < 4; ++fm)   // single b128, conflict-free (permuted)
        vf[fm] = *fragp(sm.kv[p][1][cur], fm * 16 + l16, ks * 32 + quad * 8);
      __builtin_amdgcn_s_setprio(1);
      #pragma unroll
      for (int fn = 0; fn < 4; ++fn)
        lacc[fn] = mfma_bf16(ones, pb[ks][fn].v, lacc[fn]);
      #pragma unroll
      for (int fm = 0; fm < 4; ++fm)
        #pragma unroll
        for (int fn = 0; fn < 4; ++fn)
          oacc[fm][fn] = mfma_bf16(vf[fm], pb[ks][fn].v, oacc[fm][fn]);
      __builtin_amdgcn_s_setprio(0);
    }
  }

  if (quad == 0)
    #pragma unroll
    for (int fn = 0; fn < 4; ++fn)
      Lsum[p][tw * 64 + fn * 16 + l16] = lacc[fn][0];

  __syncthreads();   // Lsum visible; K/V reads done -> om may alias

  if (p == 1) {
    #pragma unroll
    for (int fm = 0; fm < 4; ++fm)
      #pragma unroll
      for (int fn = 0; fn < 4; ++fn)
        #pragma unroll
        for (int r = 0; r < 4; ++r)
          sm.om[tw][(fm * 16 + quad * 4 + r) * 64 + fn * 16 + l16] = oacc[fm][fn][r];
  }
  if (tid < 128) {
    const float linv = 1.0f / (Lsum[0][tid] + Lsum[1][tid]);
    LinvS[tid] = linv;
    linv_ws[bh * TT + t0 + tid] = linv;
  }
  __syncthreads();

  if (p == 0) {
    float li[4];
    #pragma unroll
    for (int fn = 0; fn < 4; ++fn) li[fn] = LinvS[tw * 64 + fn * 16 + l16];
    #pragma unroll
    for (int fm = 0; fm < 4; ++fm)
      #pragma unroll
      for (int fn = 0; fn < 4; ++fn) {
        const int t = t0 + tw * 64 + fn * 16 + l16;
        B4 o;
        __bf16* op = &o.a0;
        #pragma unroll
        for (int r = 0; r < 4; ++r) {
          const float v = (oacc[fm][fn][r] +
              sm.om[tw][(fm * 16 + quad * 4 + r) * 64 + fn * 16 + l16]) * li[fn];
          op[r] = (__bf16)v;
        }
        *(B4*)(ob + ((size_t)t * BBATCH + b) * EE + h * HD + fm * 16 + quad * 4) = o;
      }
  }
}

// ---------------- avg_w body (r2 form) -----------------------------------
__device__ void avg_body(const __bf16* __restrict__ qb,
                         const __bf16* __restrict__ kb,
                         const float* __restrict__ linv_ws,
                         float* __restrict__ avg_out, int bx,
                         __bf16* Qs0, __bf16* Qs1,
                         __bf16* Ks0, __bf16* Ks1) {
  const int tid = threadIdx.x, lane = tid & 63, w = tid >> 6;
  const int wm = w >> 1, wn = w & 1;
  const int quad = lane >> 4, l16 = lane & 15;

  const int xcd = bx & 7, slot = bx >> 3;
  const int bti = xcd * 4 + (slot >> 4);
  const int s0 = (slot & 15) * 128;
  const int b = bti >> 4, t0 = (bti & 15) * 128;

  const __bf16* qt = qb + (((size_t)b * HN) * TT + t0) * HD;
  const __bf16* kt = kb + (((size_t)b * HN) * TT + s0) * HD;
  const float* lrow0 = linv_ws + ((size_t)b * HN) * TT + t0 + wm * 64;

  #pragma unroll
  for (int c = 0; c < 4; ++c) {
    stage8(qt, HD, Qs0, w * 32 + c * 8, lane);
    stage8(kt, HD, Ks0, w * 32 + c * 8, lane);
  }

  f32x4 aacc[4][4] = {};

  for (int h = 0; h < HN; ++h) {
    const int cur = h & 1;
    barrier_fence();
    if (h + 1 < HN) {
      const __bf16* qn = qt + (size_t)(h + 1) * TT * HD;
      const __bf16* kn = kt + (size_t)(h + 1) * TT * HD;
      __bf16* Qn = cur ? Qs0 : Qs1;
      __bf16* Kn = cur ? Ks0 : Ks1;
      #pragma unroll
      for (int c = 0; c < 4; ++c) {
        stage8(qn, HD, Qn, w * 32 + c * 8, lane);
        stage8(kn, HD, Kn, w * 32 + c * 8, lane);
      }
      asm volatile("s_waitcnt vmcnt(8)" ::: "memory");
    } else {
      asm volatile("s_waitcnt vmcnt(0)" ::: "memory");
    }
    barrier_fence();

    const __bf16* Qc = cur ? Qs1 : Qs0;
    const __bf16* Kc = cur ? Ks1 : Ks0;
    f32x4 sacc[4][4] = {};
    #pragma unroll
    for (int ks = 0; ks < 2; ++ks) {
      bfrag qf4[4], kf4[4];
      #pragma unroll
      for (int f = 0; f < 4; ++f)
        qf4[f] = *fragp(Qc, wm * 64 + f * 16 + l16, ks * 32 + quad * 8);
      #pragma unroll
      for (int f = 0; f < 4; ++f)
        kf4[f] = *fragp(Kc, wn * 64 + f * 16 + l16, ks * 32 + quad * 8);
      #pragma unroll
      for (int fm = 0; fm < 4; ++fm)
        #pragma unroll
        for (int fn = 0; fn < 4; ++fn)
          sacc[fm][fn] = mfma_bf16(qf4[fm], kf4[fn], sacc[fm][fn]);
    }

    const float* lr = lrow0 + (size_t)h * TT;
    f32x4 lvv[4];
    #pragma unroll
    for (int fm = 0; fm < 4; ++fm)
      lvv[fm] = *(const f32x4*)(lr + fm * 16 + quad * 4);

    #pragma unroll
    for (int fm = 0; fm < 4; ++fm)
      #pragma unroll
      for (int fn = 0; fn < 4; ++fn)
        #pragma unroll
        for (int r = 0; r < 4; ++r)
          aacc[fm][fn][r] += __builtin_amdgcn_exp2f(sacc[fm][fn][r]) * lvv[fm][r];
  }

  const float invh = 1.0f / (float)HN;
  #pragma unroll
  for (int fm = 0; fm < 4; ++fm)
    #pragma unroll
    for (int r = 0; r < 4; ++r) {
      const int t = t0 + wm * 64 + fm * 16 + quad * 4 + r;
      #pragma unroll
      for (int fn = 0; fn < 4; ++fn) {
        const int s = s0 + wn * 64 + fn * 16 + l16;
        avg_out[((size_t)b * TT + t) * TT + s] = aacc[fm][fn][r] * invh;
      }
    }
}

// ---------------- tail: avg_attn (blocks 0..511) + gemm_o (512..1023) ----
struct TailAvg { __bf16 Qs[2][128 * 64]; __bf16 Ks[2][128 * 64]; };  // 64KB
struct TailGo  { __bf16 As[2][64 * 64];  __bf16 Bs[2][128 * 64]; }; // 48KB
union TailSh { TailAvg a; TailGo g; };

__global__ __launch_bounds__(256, 2) void tail_fused(
    const __bf16* __restrict__ qb, const __bf16* __restrict__ kb,
    const float* __restrict__ linv_ws, float* __restrict__ avg_out,
    const __bf16* __restrict__ ob, const __bf16* __restrict__ wo,
    const float* __restrict__ bo, float* __restrict__ out) {
  __shared__ TailSh sh;
  const int bx = blockIdx.x;
  if (bx < 512) {
    avg_body(qb, kb, linv_ws, avg_out, bx,
             sh.a.Qs[0], sh.a.Qs[1], sh.a.Ks[0], sh.a.Ks[1]);
  } else {
    const int b2 = bx - 512;
    const int m = b2 & 63, n = b2 >> 6;
    gemm2<64>(ob, wo, bo, out, 3, 1.0f, m * 64, n * 128,
              sh.g.As[0], sh.g.As[1], sh.g.Bs[0], sh.g.Bs[1]);
  }
}

extern "C" void kernel_launch(void* const* d_in, const int* in_sizes, int n_in,
                              void* d_out, int out_size, void* d_ws, size_t ws_size,
                              hipStream_t stream) {
  (void)in_sizes; (void)n_in; (void)out_size; (void)ws_size;
  const float* query = (const float*)d_in[0];
  const float* key   = (const float*)d_in[1];
  const float* value = (const float*)d_in[2];
  const float* Wq = (const float*)d_in[3];
  const float* bq = (const float*)d_in[4];
  const float* Wk = (const float*)d_in[5];
  const float* bk = (const float*)d_in[6];
  const float* Wv = (const float*)d_in[7];
  const float* bv = (const float*)d_in[8];
  const float* Wo = (const float*)d_in[9];
  const float* bo = (const float*)d_in[10];

  char* ws = (char*)d_ws;
  size_t off = 0;
  auto wsalloc = [&](size_t bytes) -> void* {
    void* p = ws + off;
    off += (bytes + 255) & ~(size_t)255;
    return p;
  };
  const size_t XE = (size_t)MM * EE;
  const size_t WE = (size_t)EE * EE;
  __bf16* xq   = (__bf16*)wsalloc(XE * 2);
  __bf16* xk   = (__bf16*)wsalloc(XE * 2);
  __bf16* xv   = (__bf16*)wsalloc(XE * 2);
  __bf16* wqb  = (__bf16*)wsalloc(WE * 2);
  __bf16* wkb  = (__bf16*)wsalloc(WE * 2);
  __bf16* wvb  = (__bf16*)wsalloc(WE * 2);
  __bf16* wob  = (__bf16*)wsalloc(WE * 2);
  __bf16* qbuf = (__bf16*)wsalloc(XE * 2);
  __bf16* kbuf = (__bf16*)wsalloc(XE * 2);
  __bf16* vtbuf= (__bf16*)wsalloc(XE * 2);
  __bf16* obuf = (__bf16*)wsalloc(XE * 2);
  float* linv  = (float*)wsalloc((size_t)BBATCH * HN * TT * 4);

  CvtArgs ca;
  ca.src[0] = query; ca.dst[0] = xq;  ca.n4[0] = (int)(XE / 4);
  ca.src[1] = key;   ca.dst[1] = xk;  ca.n4[1] = (int)(XE / 4);
  ca.src[2] = value; ca.dst[2] = xv;  ca.n4[2] = (int)(XE / 4);
  ca.src[3] = Wq;    ca.dst[3] = wqb; ca.n4[3] = (int)(WE / 4);
  ca.src[4] = Wk;    ca.dst[4] = wkb; ca.n4[4] = (int)(WE / 4);
  ca.src[5] = Wv;    ca.dst[5] = wvb; ca.n4[5] = (int)(WE / 4);
  ca.src[6] = Wo;    ca.dst[6] = wob; ca.n4[6] = (int)(WE / 4);
  cvt_all<<<dim3(4096, 1, 7), 256, 0, stream>>>(ca);

  gemm_qkv<<<dim3(768), 256, 0, stream>>>(xq, xk, xv, wqb, wkb, wvb,
                                          bq, bk, bv, qbuf, kbuf, vtbuf);

  attn_fwd<<<dim3(512), 256, 0, stream>>>(qbuf, kbuf, vtbuf, obuf, linv);

  float* avg_out = (float*)d_out + (size_t)TT * BBATCH * EE;
  tail_fused<<<dim3(1024), 256, 0, stream>>>(qbuf, kbuf, linv, avg_out,
                                             obuf, wob, bo, (float*)d_out);
}